// Round 10
// baseline (222.633 us; speedup 1.0000x reference)
//
#include <hip/hip_runtime.h>

#define H_ 256
#define P_ 16
#define KOCC 8
#define KSUBJ 16
#define O_ 128
#define CAPMAX 2048

typedef __attribute__((ext_vector_type(8))) __bf16 bf16x8;
typedef __attribute__((ext_vector_type(4))) float f32x4;

__device__ __forceinline__ bf16x8 load_bf8(const float* p) {
  float4 a = *(const float4*)p;
  float4 b = *(const float4*)(p + 4);
  bf16x8 r;
  r[0] = (__bf16)a.x; r[1] = (__bf16)a.y; r[2] = (__bf16)a.z; r[3] = (__bf16)a.w;
  r[4] = (__bf16)b.x; r[5] = (__bf16)b.y; r[6] = (__bf16)b.z; r[7] = (__bf16)b.w;
  return r;
}

__device__ __forceinline__ bf16x8 cvt_bf8(float4 a, float4 b) {
  bf16x8 r;
  r[0] = (__bf16)a.x; r[1] = (__bf16)a.y; r[2] = (__bf16)a.z; r[3] = (__bf16)a.w;
  r[4] = (__bf16)b.x; r[5] = (__bf16)b.y; r[6] = (__bf16)b.z; r[7] = (__bf16)b.w;
  return r;
}

// Pass 1: bucket rows by global occurrence id. 32 blocks x 1024 thr x 4 elems:
// LDS histogram -> 4096 global atomics total, only 32-deep per counter.
__global__ __launch_bounds__(1024) void scatter_kernel(
    const int* __restrict__ xp, const int* __restrict__ xo,
    int* counts, int* brows, int n, int cap) {
  __shared__ int hist[O_];
  __shared__ int basev[O_];
  int tid = threadIdx.x;
  if (tid < O_) hist[tid] = 0;
  __syncthreads();
  int base_i = blockIdx.x * 4096 + tid;
  int be[4], pos[4];
#pragma unroll
  for (int e = 0; e < 4; ++e) {
    int i = base_i + e * 1024;
    pos[e] = -1;
    if (i < n) {
      be[e] = xp[i] * KOCC + xo[i];
      pos[e] = atomicAdd(&hist[be[e]], 1);
    }
  }
  __syncthreads();
  if (tid < O_) basev[tid] = atomicAdd(&counts[tid], hist[tid]);
  __syncthreads();
#pragma unroll
  for (int e = 0; e < 4; ++e) {
    if (pos[e] >= 0) {
      int idx = basev[be[e]] + pos[e];
      if (idx < cap) brows[be[e] * cap + idx] = base_i + e * 1024;
    }
  }
}

// Pass 2: grid 2048 = 128 buckets x 16 chunks of 64 rows, 4 waves/block.
// Epilogue: MFMA accumulators round-trip through a wave-private LDS scratch
// ([head][row][col]) so each softmax is an in-register VALU reduction on one
// lane (16 v_exp + 15 adds) instead of a 5-deep ds_bpermute chain.
// R10 fix: __shfl(subjv, rr) hoisted OUT of the head-select ternary — under
// divergence ds_bpermute returns 0 for inactive source lanes, which silently
// redirected every subj target to class 0 (R9's output-2 1.4e-2 failure).
__global__ __launch_bounds__(256, 4) void hsm_main(
    const float* __restrict__ X,
    const float* __restrict__ Wp, const float* __restrict__ bp,
    const float* __restrict__ Wo, const float* __restrict__ bo,
    const float* __restrict__ Ws, const float* __restrict__ bs,
    const int* __restrict__ subj,
    const int* __restrict__ counts, const int* __restrict__ brows,
    float* __restrict__ out, int n, int cap) {
  int b = blockIdx.x & 127;      // bucket; chunks of a bucket share an XCD
  int chunk = blockIdx.x >> 7;   // 0..15, 64 rows each
  int count = counts[b];
  if (count > cap) count = cap;
  int p = b >> 3;
  int occl = b & 7;

  __shared__ __bf16 Bf[3 * 8 * 64 * 8];   // 24 KB weight fragments
  __shared__ float S[4][3 * 16 * 16];     // 12 KB wave-private transpose scratch

  // --- Stage B fragments into LDS: [head][kk][lane] x 8 bf16 (16 B) ---
  {
    int t = threadIdx.x;
#pragma unroll
    for (int it = 0; it < 6; ++it) {
      int fid = it * 256 + t;          // 0..1535
      int lane_f = fid & 63;
      int hk = fid >> 6;               // 0..23
      int head = hk >> 3, kk = hk & 7;
      int colf = lane_f & 15, quadf = lane_f >> 4;
      const float* src;
      if (head == 0)      src = Wp + colf * H_;
      else if (head == 1) src = Wo + (p * KOCC + (colf & 7)) * H_;
      else                src = Ws + (b * KSUBJ + colf) * H_;
      bf16x8 v = load_bf8(src + kk * 32 + quadf * 8);
      *(bf16x8*)&Bf[(size_t)fid * 8] = v;
    }
  }
  __syncthreads();

  int lane = threadIdx.x & 63;
  int wave = threadIdx.x >> 6;
  int col = lane & 15;
  int quad = lane >> 4;

  const int* brow_b = brows + b * cap;
  const bf16x8* Bfrag = (const bf16x8*)Bf;
  float* Sw = S[wave];

  int rr = lane & 15;            // reader: row index
  int hh = lane >> 4;            // reader: head (3 = idle)

  bool v1 = col < KOCC;
  float bias0 = bp[col];
  float bias1 = v1 ? bo[p * KOCC + col] : 0.0f;
  float bias2 = bs[b * KSUBJ + col];

  for (int base = chunk * 64 + wave * 16; base < count; base += 1024) {
    int rem = count - base;        // valid rows in this 16-group (>=1)
    int rida = brow_b[base + (col < rem ? col : rem - 1)];
    int subjv = subj[rida];        // lane col holds subj target for local row col
    const float* xr = X + (size_t)rida * H_ + quad * 8;

    // Batch-issue all 16 X loads; fence prevents cvt/mfma hoisting above.
    float4 ta[8], tb[8];
#pragma unroll
    for (int kk = 0; kk < 8; ++kk) {
      const float4* s = (const float4*)(xr + kk * 32);
      ta[kk] = s[0];
      tb[kk] = s[1];
    }
    __builtin_amdgcn_sched_barrier(0);

    f32x4 acc0 = {0.f, 0.f, 0.f, 0.f};
    f32x4 acc1 = {0.f, 0.f, 0.f, 0.f};
    f32x4 acc2 = {0.f, 0.f, 0.f, 0.f};
#pragma unroll
    for (int kk = 0; kk < 8; ++kk) {
      bf16x8 a = cvt_bf8(ta[kk], tb[kk]);
      acc0 = __builtin_amdgcn_mfma_f32_16x16x32_bf16(a, Bfrag[kk * 64 + lane], acc0, 0, 0, 0);
      acc1 = __builtin_amdgcn_mfma_f32_16x16x32_bf16(a, Bfrag[(8 + kk) * 64 + lane], acc1, 0, 0, 0);
      acc2 = __builtin_amdgcn_mfma_f32_16x16x32_bf16(a, Bfrag[(16 + kk) * 64 + lane], acc2, 0, 0, 0);
    }

    // --- Transpose accumulators to LDS (bias folded in at write) ---
    // Same-wave DS ordering guarantees the reads below see these writes.
#pragma unroll
    for (int r = 0; r < 4; ++r) {
      int row = quad * 4 + r;
      Sw[0 * 256 + row * 16 + col] = acc0[r] + bias0;
      Sw[1 * 256 + row * 16 + col] = acc1[r] + bias1;
      Sw[2 * 256 + row * 16 + col] = acc2[r] + bias2;
    }

    // Uniform-exec shuffle BEFORE any head-dependent selection (ds_bpermute
    // from an inactive source lane returns 0 — must run with all lanes on).
    int tsub_r = __shfl(subjv, rr);

    // --- Per-(row,head) softmax on one lane, pure VALU ---
    float prob;
    {
      const float* Lx = Sw + (hh < 3 ? hh * 256 : 0) + rr * 16;
      float4 c0 = *(const float4*)(Lx + 0);
      float4 c1 = *(const float4*)(Lx + 4);
      float4 c2 = *(const float4*)(Lx + 8);
      float4 c3 = *(const float4*)(Lx + 12);
      int tgt = (hh == 0) ? p : ((hh == 1) ? occl : tsub_r);
      float lt = Lx[tgt];
      float den;
      if (hh == 1) {
        den = __expf(c0.x) + __expf(c0.y) + __expf(c0.z) + __expf(c0.w)
            + __expf(c1.x) + __expf(c1.y) + __expf(c1.z) + __expf(c1.w);
      } else {
        den = __expf(c0.x) + __expf(c0.y) + __expf(c0.z) + __expf(c0.w)
            + __expf(c1.x) + __expf(c1.y) + __expf(c1.z) + __expf(c1.w)
            + __expf(c2.x) + __expf(c2.y) + __expf(c2.z) + __expf(c2.w)
            + __expf(c3.x) + __expf(c3.y) + __expf(c3.z) + __expf(c3.w);
      }
      prob = __expf(lt) / den;
    }
    // --- Combine heads: lanes 0..15 gather p1 (lane+16) and p2 (lane+32) ---
    float p1v = __shfl(prob, (lane + 16) & 63);
    float p2v = __shfl(prob, (lane + 32) & 63);
    if (hh == 0 && rr < rem) {
      float po = prob * p1v;
      out[rida] = prob;            // lane rr (col==rr) holds rida of row rr
      out[n + rida] = po;
      out[2 * n + rida] = po * p2v;
    }
  }
}

extern "C" void kernel_launch(void* const* d_in, const int* in_sizes, int n_in,
                              void* d_out, int out_size, void* d_ws, size_t ws_size,
                              hipStream_t stream) {
  const float* X  = (const float*)d_in[0];
  const float* Wp = (const float*)d_in[1];
  const float* bp = (const float*)d_in[2];
  const float* Wo = (const float*)d_in[3];
  const float* bo = (const float*)d_in[4];
  const float* Ws = (const float*)d_in[5];
  const float* bs = (const float*)d_in[6];
  const int* xp   = (const int*)d_in[7];
  const int* xo   = (const int*)d_in[8];
  const int* xs   = (const int*)d_in[9];
  float* out = (float*)d_out;
  int n = in_sizes[7];

  int* wsI = (int*)d_ws;
  int* counts = wsI;            // 128 ints
  int* brows = wsI + 128;       // 128 * cap ints
  long avail = (long)(ws_size / 4) - 128;
  int cap = (int)(avail / O_);
  if (cap > CAPMAX) cap = CAPMAX;
  if (cap < 1) cap = 1;

  hipMemsetAsync(counts, 0, O_ * sizeof(int), stream);
  scatter_kernel<<<dim3((n + 4095) / 4096), dim3(1024), 0, stream>>>(xp, xo, counts, brows, n, cap);
  hsm_main<<<dim3(O_ * 16), dim3(256), 0, stream>>>(X, Wp, bp, Wo, bo, Ws, bs, xs,
                                                    counts, brows, out, n, cap);
}